// Round 3
// baseline (280.374 us; speedup 1.0000x reference)
//
#include <hip/hip_runtime.h>
#include <cstdint>

#define NNODES 100000
#define NEDGES 1200000
#define INF 64
#define OUTF 32
#define SCAN_B 256
#define NBLK ((NNODES + SCAN_B - 1) / SCAN_B)   // 391

// ---- degree histogram (int) ----
__global__ __launch_bounds__(256) void k_hist(const int* __restrict__ dst,
                                              int* __restrict__ degi) {
    int i = blockIdx.x * 256 + threadIdx.x;
    if (i < NEDGES) atomicAdd(&degi[dst[i]], 1);
}

// ---- norm = rsqrt(max(deg,1)) ----
__global__ __launch_bounds__(256) void k_norm(const int* __restrict__ degi,
                                              float* __restrict__ norm) {
    int i = blockIdx.x * 256 + threadIdx.x;
    if (i < NNODES) {
        int d = degi[i];
        norm[i] = rsqrtf(d < 1 ? 1.0f : (float)d);
    }
}

// ---- scan step 1: per-block sums ----
__global__ __launch_bounds__(SCAN_B) void k_scan1(const int* __restrict__ degi,
                                                  int* __restrict__ bsum) {
    __shared__ int s[SCAN_B];
    int i = blockIdx.x * SCAN_B + threadIdx.x;
    s[threadIdx.x] = (i < NNODES) ? degi[i] : 0;
    __syncthreads();
    for (int st = SCAN_B / 2; st > 0; st >>= 1) {
        if (threadIdx.x < st) s[threadIdx.x] += s[threadIdx.x + st];
        __syncthreads();
    }
    if (threadIdx.x == 0) bsum[blockIdx.x] = s[0];
}

// ---- scan step 2: exclusive scan of block sums (single block) ----
__global__ __launch_bounds__(512) void k_scan2(int* __restrict__ bsum) {
    __shared__ int s[512];
    int t = threadIdx.x;
    int v = (t < NBLK) ? bsum[t] : 0;
    s[t] = v;
    __syncthreads();
    for (int st = 1; st < 512; st <<= 1) {
        int add = (t >= st) ? s[t - st] : 0;
        __syncthreads();
        s[t] += add;
        __syncthreads();
    }
    if (t < NBLK) bsum[t] = s[t] - v;  // exclusive
}

// ---- scan step 3: rowstart (+sentinel) and rowcur (atomic cursor copy) ----
__global__ __launch_bounds__(SCAN_B) void k_scan3(const int* __restrict__ degi,
                                                  const int* __restrict__ bsum,
                                                  int* __restrict__ rowstart,
                                                  int* __restrict__ rowcur) {
    __shared__ int s[SCAN_B];
    int i = blockIdx.x * SCAN_B + threadIdx.x;
    int t = threadIdx.x;
    int v = (i < NNODES) ? degi[i] : 0;
    s[t] = v;
    __syncthreads();
    for (int st = 1; st < SCAN_B; st <<= 1) {
        int add = (t >= st) ? s[t - st] : 0;
        __syncthreads();
        s[t] += add;
        __syncthreads();
    }
    if (i < NNODES) {
        int x = bsum[blockIdx.x] + s[t] - v;
        rowstart[i] = x;
        rowcur[i] = x;
    }
    if (blockIdx.x == 0 && t == 0) rowstart[NNODES] = NEDGES;
}

// ---- fill CSR: only col (src ids); slot via atomic on rowcur ----
__global__ __launch_bounds__(256) void k_fill(const int* __restrict__ src,
                                              const int* __restrict__ dst,
                                              int* __restrict__ rowcur,
                                              int* __restrict__ col) {
    int i = blockIdx.x * 256 + threadIdx.x;
    if (i >= NEDGES) return;
    int p = atomicAdd(&rowcur[dst[i]], 1);
    col[p] = src[i];
}

// ---- u0 = norm .* (X @ W^T)  (project 64->32, pre-scaled) ----
__global__ __launch_bounds__(256) void k_project(const float* __restrict__ feat,
                                                 const float* __restrict__ W,
                                                 const float* __restrict__ norm,
                                                 float* __restrict__ u0) {
    __shared__ float Ws[OUTF][INF + 1];
    __shared__ float Fs[8][INF];
    int tid = threadIdx.x;
    for (int i = tid; i < OUTF * INF; i += 256) Ws[i / INF][i % INF] = W[i];
    int node0 = blockIdx.x * 8;
    for (int i = tid; i < 8 * INF; i += 256) {
        int n = node0 + i / INF;
        Fs[i / INF][i % INF] = (n < NNODES) ? feat[(size_t)n * INF + (i % INF)] : 0.0f;
    }
    __syncthreads();
    int ln = tid >> 5, of = tid & 31;
    int n = node0 + ln;
    if (n < NNODES) {
        float acc = 0.0f;
#pragma unroll
        for (int k = 0; k < INF; ++k) acc += Fs[ln][k] * Ws[of][k];
        u0[(size_t)n * OUTF + of] = acc * norm[n];
    }
}

// ---- one hop in u-space: uout[d] = w(d) * sum_e uin[col[e]]  (+bias) ----
// w = norm^2 for mid hops, norm for the last hop (un-scales back to h-space).
// Source-side norm is already embedded in u. 8 lanes/node, float4 each.
template <bool LAST>
__global__ __launch_bounds__(256) void k_gather(const float4* __restrict__ uin,
                                                float4* __restrict__ uout,
                                                const int* __restrict__ rowstart,
                                                const int* __restrict__ col,
                                                const float* __restrict__ norm,
                                                const float4* __restrict__ bias4) {
    int t = blockIdx.x * 256 + threadIdx.x;
    int node = t >> 3;
    if (node >= NNODES) return;
    int lane = t & 7;
    int e = rowstart[node], re = rowstart[node + 1];
    float4 acc = make_float4(0.f, 0.f, 0.f, 0.f);
    for (; e + 3 < re; e += 4) {
        int s0 = col[e], s1 = col[e + 1], s2 = col[e + 2], s3 = col[e + 3];
        float4 a = uin[(size_t)s0 * 8 + lane];
        float4 c = uin[(size_t)s1 * 8 + lane];
        float4 d = uin[(size_t)s2 * 8 + lane];
        float4 f = uin[(size_t)s3 * 8 + lane];
        acc.x += (a.x + c.x) + (d.x + f.x);
        acc.y += (a.y + c.y) + (d.y + f.y);
        acc.z += (a.z + c.z) + (d.z + f.z);
        acc.w += (a.w + c.w) + (d.w + f.w);
    }
    for (; e < re; ++e) {
        float4 a = uin[(size_t)col[e] * 8 + lane];
        acc.x += a.x; acc.y += a.y; acc.z += a.z; acc.w += a.w;
    }
    float nn = norm[node];
    float w = LAST ? nn : nn * nn;
    acc.x *= w; acc.y *= w; acc.z *= w; acc.w *= w;
    if (LAST) {
        float4 bb = bias4[lane];
        acc.x += bb.x; acc.y += bb.y; acc.z += bb.z; acc.w += bb.w;
    }
    uout[(size_t)node * 8 + lane] = acc;
}

extern "C" void kernel_launch(void* const* d_in, const int* in_sizes, int n_in,
                              void* d_out, int out_size, void* d_ws, size_t ws_size,
                              hipStream_t stream) {
    const float* feat = (const float*)d_in[0];
    const int*   src  = (const int*)d_in[1];
    const int*   dst  = (const int*)d_in[2];
    const float* W    = (const float*)d_in[3];
    const float* b    = (const float*)d_in[4];
    float* out = (float*)d_out;

    char* ws = (char*)d_ws;
    size_t off = 0;
    auto alloc = [&](size_t bytes) {
        void* p = ws + off;
        off = (off + bytes + 255) & ~(size_t)255;
        return p;
    };
    int*   degi     = (int*)alloc((size_t)NNODES * 4);
    float* norm     = (float*)alloc((size_t)NNODES * 4);
    int*   rowstart = (int*)alloc(((size_t)NNODES + 1) * 4);
    int*   rowcur   = (int*)alloc((size_t)NNODES * 4);
    int*   bsum     = (int*)alloc((size_t)NBLK * 4);
    int*   col      = (int*)alloc((size_t)NEDGES * 4);
    float* h0       = (float*)alloc((size_t)NNODES * OUTF * 4);
    float* h1       = (float*)alloc((size_t)NNODES * OUTF * 4);

    // ---- build CSR ----
    hipMemsetAsync(degi, 0, (size_t)NNODES * 4, stream);
    k_hist<<<(NEDGES + 255) / 256, 256, 0, stream>>>(dst, degi);
    k_norm<<<(NNODES + 255) / 256, 256, 0, stream>>>(degi, norm);
    k_scan1<<<NBLK, SCAN_B, 0, stream>>>(degi, bsum);
    k_scan2<<<1, 512, 0, stream>>>(bsum);
    k_scan3<<<NBLK, SCAN_B, 0, stream>>>(degi, bsum, rowstart, rowcur);
    k_fill<<<(NEDGES + 255) / 256, 256, 0, stream>>>(src, dst, rowcur, col);

    // ---- project 64 -> 32, pre-scale by norm ----
    k_project<<<(NNODES + 7) / 8, 256, 0, stream>>>(feat, W, norm, h0);

    // ---- 4 hops, no atomics, no per-edge weights ----
    const int ggrid = (NNODES * 8 + 255) / 256;
    k_gather<false><<<ggrid, 256, 0, stream>>>((const float4*)h0, (float4*)h1,
                                               rowstart, col, norm, nullptr);
    k_gather<false><<<ggrid, 256, 0, stream>>>((const float4*)h1, (float4*)h0,
                                               rowstart, col, norm, nullptr);
    k_gather<false><<<ggrid, 256, 0, stream>>>((const float4*)h0, (float4*)h1,
                                               rowstart, col, norm, nullptr);
    k_gather<true><<<ggrid, 256, 0, stream>>>((const float4*)h1, (float4*)out,
                                              rowstart, col, norm,
                                              (const float4*)b);
}

// Round 4
// 214.212 us; speedup vs baseline: 1.3089x; 1.3089x over previous
//
#include <hip/hip_runtime.h>
#include <cstdint>

#define NNODES 100000
#define NEDGES 1200000
#define INF 64
#define OUTF 32
#define SCAN_B 256
#define NBUCK ((NNODES + SCAN_B - 1) / SCAN_B)   // 391; bucket b = dst >> 8
#define PLACE_CAP 4608                            // max edges/bucket (mean 3072, sd 55)
#define BIN_EPT 16                                // edges per thread in k_bin
#define BIN_THREADS (NEDGES / BIN_EPT)            // 75000
#define CUR_PAD 16                                // 64B padding for global cursors

// ---- per-node degree histogram ----
__global__ __launch_bounds__(256) void k_hist(const int* __restrict__ dst,
                                              int* __restrict__ degi) {
    int i = blockIdx.x * 256 + threadIdx.x;
    if (i < NEDGES) atomicAdd(&degi[dst[i]], 1);
}

// ---- norm = rsqrt(max(deg,1)) ----
__global__ __launch_bounds__(256) void k_norm(const int* __restrict__ degi,
                                              float* __restrict__ norm) {
    int i = blockIdx.x * 256 + threadIdx.x;
    if (i < NNODES) {
        int d = degi[i];
        norm[i] = rsqrtf(d < 1 ? 1.0f : (float)d);
    }
}

// ---- scan step 1: per-256-node block sums == per-bucket edge counts ----
__global__ __launch_bounds__(SCAN_B) void k_scan1(const int* __restrict__ degi,
                                                  int* __restrict__ bsum) {
    __shared__ int s[SCAN_B];
    int i = blockIdx.x * SCAN_B + threadIdx.x;
    s[threadIdx.x] = (i < NNODES) ? degi[i] : 0;
    __syncthreads();
    for (int st = SCAN_B / 2; st > 0; st >>= 1) {
        if (threadIdx.x < st) s[threadIdx.x] += s[threadIdx.x + st];
        __syncthreads();
    }
    if (threadIdx.x == 0) bsum[blockIdx.x] = s[0];
}

// ---- scan step 2: exclusive scan -> bucket bases; also init padded cursors ----
__global__ __launch_bounds__(512) void k_scan2(int* __restrict__ bsum,
                                               int* __restrict__ gcur) {
    __shared__ int s[512];
    int t = threadIdx.x;
    int v = (t < NBUCK) ? bsum[t] : 0;
    s[t] = v;
    __syncthreads();
    for (int st = 1; st < 512; st <<= 1) {
        int add = (t >= st) ? s[t - st] : 0;
        __syncthreads();
        s[t] += add;
        __syncthreads();
    }
    if (t < NBUCK) {
        int ex = s[t] - v;        // exclusive
        bsum[t] = ex;
        gcur[t * CUR_PAD] = ex;
    }
}

// ---- scan step 3: per-node rowstart (+sentinel) ----
__global__ __launch_bounds__(SCAN_B) void k_scan3(const int* __restrict__ degi,
                                                  const int* __restrict__ bsum,
                                                  int* __restrict__ rowstart) {
    __shared__ int s[SCAN_B];
    int i = blockIdx.x * SCAN_B + threadIdx.x;
    int t = threadIdx.x;
    int v = (i < NNODES) ? degi[i] : 0;
    s[t] = v;
    __syncthreads();
    for (int st = 1; st < SCAN_B; st <<= 1) {
        int add = (t >= st) ? s[t - st] : 0;
        __syncthreads();
        s[t] += add;
        __syncthreads();
    }
    if (i < NNODES) rowstart[i] = bsum[blockIdx.x] + s[t] - v;
    if (blockIdx.x == 0 && t == 0) rowstart[NNODES] = NEDGES;
}

// ---- pass 1: bin edges by bucket, packed (dlow<<17 | src) ----
__global__ __launch_bounds__(256) void k_bin(const int4* __restrict__ src4,
                                             const int4* __restrict__ dst4,
                                             int* __restrict__ gcur,
                                             unsigned* __restrict__ packed) {
    __shared__ int cnt[NBUCK];
    __shared__ int base[NBUCK];
    int tid = threadIdx.x;
    for (int i = tid; i < NBUCK; i += 256) cnt[i] = 0;
    __syncthreads();
    int gid = blockIdx.x * 256 + tid;
    bool act = gid < BIN_THREADS;
    int4 s4[4], d4[4];
    if (act) {
#pragma unroll
        for (int k = 0; k < 4; ++k) {
            s4[k] = src4[(size_t)gid * 4 + k];
            d4[k] = dst4[(size_t)gid * 4 + k];
            atomicAdd(&cnt[d4[k].x >> 8], 1);
            atomicAdd(&cnt[d4[k].y >> 8], 1);
            atomicAdd(&cnt[d4[k].z >> 8], 1);
            atomicAdd(&cnt[d4[k].w >> 8], 1);
        }
    }
    __syncthreads();
    for (int i = tid; i < NBUCK; i += 256) {
        int c = cnt[i];
        base[i] = c ? atomicAdd(&gcur[i * CUR_PAD], c) : 0;
        cnt[i] = 0;
    }
    __syncthreads();
    if (act) {
#pragma unroll
        for (int k = 0; k < 4; ++k) {
            int ss[4] = {s4[k].x, s4[k].y, s4[k].z, s4[k].w};
            int dd[4] = {d4[k].x, d4[k].y, d4[k].z, d4[k].w};
#pragma unroll
            for (int j = 0; j < 4; ++j) {
                int b = dd[j] >> 8;
                int rel = atomicAdd(&cnt[b], 1);
                packed[base[b] + rel] =
                    ((unsigned)(dd[j] & 255) << 17) | (unsigned)ss[j];
            }
        }
    }
}

// ---- pass 2: one block per bucket; LDS scatter -> coalesced col write ----
__global__ __launch_bounds__(256) void k_place(const unsigned* __restrict__ packed,
                                               const int* __restrict__ rowstart,
                                               const int* __restrict__ bsum,
                                               int* __restrict__ col) {
    __shared__ int cur[SCAN_B];
    __shared__ int stage[PLACE_CAP];
    int b = blockIdx.x, tid = threadIdx.x;
    int node0 = b * SCAN_B;
    int nn = (NNODES - node0 < SCAN_B) ? (NNODES - node0) : SCAN_B;
    int slot_base = rowstart[node0];
    int nedge = rowstart[node0 + nn] - slot_base;
    if (tid < nn) cur[tid] = rowstart[node0 + tid] - slot_base;
    __syncthreads();
    int ebase = bsum[b];
    for (int i = tid; i < nedge; i += 256) {
        unsigned pk = packed[ebase + i];
        int rel = atomicAdd(&cur[pk >> 17], 1);
        stage[rel] = (int)(pk & 0x1FFFFu);
    }
    __syncthreads();
    for (int i = tid; i < nedge; i += 256) col[slot_base + i] = stage[i];
}

// ---- u0 = norm .* (X @ W^T) ----
__global__ __launch_bounds__(256) void k_project(const float* __restrict__ feat,
                                                 const float* __restrict__ W,
                                                 const float* __restrict__ norm,
                                                 float* __restrict__ u0) {
    __shared__ float Ws[OUTF][INF + 1];
    __shared__ float Fs[8][INF];
    int tid = threadIdx.x;
    for (int i = tid; i < OUTF * INF; i += 256) Ws[i / INF][i % INF] = W[i];
    int node0 = blockIdx.x * 8;
    for (int i = tid; i < 8 * INF; i += 256) {
        int n = node0 + i / INF;
        Fs[i / INF][i % INF] = (n < NNODES) ? feat[(size_t)n * INF + (i % INF)] : 0.0f;
    }
    __syncthreads();
    int ln = tid >> 5, of = tid & 31;
    int n = node0 + ln;
    if (n < NNODES) {
        float acc = 0.0f;
#pragma unroll
        for (int k = 0; k < INF; ++k) acc += Fs[ln][k] * Ws[of][k];
        u0[(size_t)n * OUTF + of] = acc * norm[n];
    }
}

// ---- one hop in u-space: uout[d] = w(d) * sum_e uin[col[e]]  (+bias) ----
template <bool LAST>
__global__ __launch_bounds__(256) void k_gather(const float4* __restrict__ uin,
                                                float4* __restrict__ uout,
                                                const int* __restrict__ rowstart,
                                                const int* __restrict__ col,
                                                const float* __restrict__ norm,
                                                const float4* __restrict__ bias4) {
    int t = blockIdx.x * 256 + threadIdx.x;
    int node = t >> 3;
    if (node >= NNODES) return;
    int lane = t & 7;
    int e = rowstart[node], re = rowstart[node + 1];
    float4 acc = make_float4(0.f, 0.f, 0.f, 0.f);
    for (; e + 7 < re; e += 8) {
        int s0 = col[e],     s1 = col[e + 1], s2 = col[e + 2], s3 = col[e + 3];
        int s4 = col[e + 4], s5 = col[e + 5], s6 = col[e + 6], s7 = col[e + 7];
        float4 a0 = uin[(size_t)s0 * 8 + lane];
        float4 a1 = uin[(size_t)s1 * 8 + lane];
        float4 a2 = uin[(size_t)s2 * 8 + lane];
        float4 a3 = uin[(size_t)s3 * 8 + lane];
        float4 a4 = uin[(size_t)s4 * 8 + lane];
        float4 a5 = uin[(size_t)s5 * 8 + lane];
        float4 a6 = uin[(size_t)s6 * 8 + lane];
        float4 a7 = uin[(size_t)s7 * 8 + lane];
        acc.x += ((a0.x + a1.x) + (a2.x + a3.x)) + ((a4.x + a5.x) + (a6.x + a7.x));
        acc.y += ((a0.y + a1.y) + (a2.y + a3.y)) + ((a4.y + a5.y) + (a6.y + a7.y));
        acc.z += ((a0.z + a1.z) + (a2.z + a3.z)) + ((a4.z + a5.z) + (a6.z + a7.z));
        acc.w += ((a0.w + a1.w) + (a2.w + a3.w)) + ((a4.w + a5.w) + (a6.w + a7.w));
    }
    for (; e + 3 < re; e += 4) {
        int s0 = col[e], s1 = col[e + 1], s2 = col[e + 2], s3 = col[e + 3];
        float4 a0 = uin[(size_t)s0 * 8 + lane];
        float4 a1 = uin[(size_t)s1 * 8 + lane];
        float4 a2 = uin[(size_t)s2 * 8 + lane];
        float4 a3 = uin[(size_t)s3 * 8 + lane];
        acc.x += (a0.x + a1.x) + (a2.x + a3.x);
        acc.y += (a0.y + a1.y) + (a2.y + a3.y);
        acc.z += (a0.z + a1.z) + (a2.z + a3.z);
        acc.w += (a0.w + a1.w) + (a2.w + a3.w);
    }
    for (; e < re; ++e) {
        float4 a = uin[(size_t)col[e] * 8 + lane];
        acc.x += a.x; acc.y += a.y; acc.z += a.z; acc.w += a.w;
    }
    float nn = norm[node];
    float w = LAST ? nn : nn * nn;
    acc.x *= w; acc.y *= w; acc.z *= w; acc.w *= w;
    if (LAST) {
        float4 bb = bias4[lane];
        acc.x += bb.x; acc.y += bb.y; acc.z += bb.z; acc.w += bb.w;
    }
    uout[(size_t)node * 8 + lane] = acc;
}

extern "C" void kernel_launch(void* const* d_in, const int* in_sizes, int n_in,
                              void* d_out, int out_size, void* d_ws, size_t ws_size,
                              hipStream_t stream) {
    const float* feat = (const float*)d_in[0];
    const int*   src  = (const int*)d_in[1];
    const int*   dst  = (const int*)d_in[2];
    const float* W    = (const float*)d_in[3];
    const float* b    = (const float*)d_in[4];
    float* out = (float*)d_out;

    char* ws = (char*)d_ws;
    size_t off = 0;
    auto alloc = [&](size_t bytes) {
        void* p = ws + off;
        off = (off + bytes + 255) & ~(size_t)255;
        return p;
    };
    int*      degi     = (int*)alloc((size_t)NNODES * 4);
    float*    norm     = (float*)alloc((size_t)NNODES * 4);
    int*      rowstart = (int*)alloc(((size_t)NNODES + 1) * 4);
    int*      bsum     = (int*)alloc((size_t)NBUCK * 4);
    int*      gcur     = (int*)alloc((size_t)NBUCK * CUR_PAD * 4);
    unsigned* packed   = (unsigned*)alloc((size_t)NEDGES * 4);
    int*      col      = (int*)alloc((size_t)NEDGES * 4);
    float*    h0       = (float*)alloc((size_t)NNODES * OUTF * 4);
    float*    h1       = (float*)alloc((size_t)NNODES * OUTF * 4);

    // ---- degree, norm, offsets (bucket histogram/base fall out of the scan) ----
    hipMemsetAsync(degi, 0, (size_t)NNODES * 4, stream);
    k_hist<<<(NEDGES + 255) / 256, 256, 0, stream>>>(dst, degi);
    k_norm<<<(NNODES + 255) / 256, 256, 0, stream>>>(degi, norm);
    k_scan1<<<NBUCK, SCAN_B, 0, stream>>>(degi, bsum);
    k_scan2<<<1, 512, 0, stream>>>(bsum, gcur);
    k_scan3<<<NBUCK, SCAN_B, 0, stream>>>(degi, bsum, rowstart);

    // ---- two-pass bucketed CSR build ----
    k_bin<<<(BIN_THREADS + 255) / 256, 256, 0, stream>>>(
        (const int4*)src, (const int4*)dst, gcur, packed);
    k_place<<<NBUCK, 256, 0, stream>>>(packed, rowstart, bsum, col);

    // ---- project 64 -> 32, pre-scaled by norm ----
    k_project<<<(NNODES + 7) / 8, 256, 0, stream>>>(feat, W, norm, h0);

    // ---- 4 hops ----
    const int ggrid = (NNODES * 8 + 255) / 256;
    k_gather<false><<<ggrid, 256, 0, stream>>>((const float4*)h0, (float4*)h1,
                                               rowstart, col, norm, nullptr);
    k_gather<false><<<ggrid, 256, 0, stream>>>((const float4*)h1, (float4*)h0,
                                               rowstart, col, norm, nullptr);
    k_gather<false><<<ggrid, 256, 0, stream>>>((const float4*)h0, (float4*)h1,
                                               rowstart, col, norm, nullptr);
    k_gather<true><<<ggrid, 256, 0, stream>>>((const float4*)h1, (float4*)out,
                                              rowstart, col, norm,
                                              (const float4*)b);
}

// Round 5
// 154.650 us; speedup vs baseline: 1.8130x; 1.3851x over previous
//
#include <hip/hip_runtime.h>
#include <cstdint>

#define NNODES 100000
#define NEDGES 1200000
#define INF 64
#define OUTF 32
#define SCAN_B 256
#define NBUCK ((NNODES + SCAN_B - 1) / SCAN_B)   // 391; bucket b = dst >> 8
#define PLACE_CAP 4608                            // fixed slots/bucket (mean 3072, sd 55; R3-verified)
#define BIN_EPT 16
#define BIN_THREADS (NEDGES / BIN_EPT)            // 75000
#define CUR_PAD 16                                // 64B-padded global cursors

// ---- cursor init: gcur[b] = b*PLACE_CAP ----
__global__ __launch_bounds__(256) void k_initcur(int* __restrict__ gcur) {
    int i = blockIdx.x * 256 + threadIdx.x;
    if (i < NBUCK) gcur[i * CUR_PAD] = i * PLACE_CAP;
}

// ---- pass 1: bin edges into fixed-capacity buckets, packed (dlow<<17 | src) ----
__global__ __launch_bounds__(256) void k_bin(const int4* __restrict__ src4,
                                             const int4* __restrict__ dst4,
                                             int* __restrict__ gcur,
                                             unsigned* __restrict__ packed) {
    __shared__ int cnt[NBUCK];
    __shared__ int base[NBUCK];
    int tid = threadIdx.x;
    for (int i = tid; i < NBUCK; i += 256) cnt[i] = 0;
    __syncthreads();
    int gid = blockIdx.x * 256 + tid;
    bool act = gid < BIN_THREADS;
    int4 s4[4], d4[4];
    if (act) {
#pragma unroll
        for (int k = 0; k < 4; ++k) {
            s4[k] = src4[(size_t)gid * 4 + k];
            d4[k] = dst4[(size_t)gid * 4 + k];
            atomicAdd(&cnt[d4[k].x >> 8], 1);
            atomicAdd(&cnt[d4[k].y >> 8], 1);
            atomicAdd(&cnt[d4[k].z >> 8], 1);
            atomicAdd(&cnt[d4[k].w >> 8], 1);
        }
    }
    __syncthreads();
    for (int i = tid; i < NBUCK; i += 256) {
        int c = cnt[i];
        base[i] = c ? atomicAdd(&gcur[i * CUR_PAD], c) : 0;
        cnt[i] = 0;
    }
    __syncthreads();
    if (act) {
#pragma unroll
        for (int k = 0; k < 4; ++k) {
            int ss[4] = {s4[k].x, s4[k].y, s4[k].z, s4[k].w};
            int dd[4] = {d4[k].x, d4[k].y, d4[k].z, d4[k].w};
#pragma unroll
            for (int j = 0; j < 4; ++j) {
                int b = dd[j] >> 8;
                int rel = atomicAdd(&cnt[b], 1);
                packed[base[b] + rel] =
                    ((unsigned)(dd[j] & 255) << 17) | (unsigned)ss[j];
            }
        }
    }
}

// ---- pass 2: per bucket: degree (LDS), norm, rowse, LDS scatter, coalesced col ----
__global__ __launch_bounds__(256) void k_place(const unsigned* __restrict__ packed,
                                               const int* __restrict__ gcur,
                                               int* __restrict__ col,
                                               int2* __restrict__ rowse,
                                               float* __restrict__ norm) {
    __shared__ unsigned sin_[PLACE_CAP];
    __shared__ int stage[PLACE_CAP];
    __shared__ int deg[SCAN_B];
    __shared__ int rs[SCAN_B];
    int b = blockIdx.x, tid = threadIdx.x;
    int node0 = b * SCAN_B;
    int nn = (NNODES - node0 < SCAN_B) ? (NNODES - node0) : SCAN_B;
    int ebase = b * PLACE_CAP;
    int nedge = gcur[b * CUR_PAD] - ebase;
    deg[tid] = 0;
    __syncthreads();
    for (int i = tid; i < nedge; i += 256) {
        unsigned pk = packed[ebase + i];
        sin_[i] = pk;
        atomicAdd(&deg[pk >> 17], 1);
    }
    __syncthreads();
    int d = deg[tid];
    rs[tid] = d;
    __syncthreads();
    for (int st = 1; st < SCAN_B; st <<= 1) {
        int add = (tid >= st) ? rs[tid - st] : 0;
        __syncthreads();
        rs[tid] += add;
        __syncthreads();
    }
    int myoff = rs[tid] - d;  // exclusive scan within bucket
    if (tid < nn) {
        norm[node0 + tid] = rsqrtf(d < 1 ? 1.0f : (float)d);
        rowse[node0 + tid] = make_int2(ebase + myoff, ebase + myoff + d);
    }
    deg[tid] = myoff;  // reuse as cursor
    __syncthreads();
    for (int i = tid; i < nedge; i += 256) {
        unsigned pk = sin_[i];
        int rel = atomicAdd(&deg[pk >> 17], 1);
        stage[rel] = (int)(pk & 0x1FFFFu);
    }
    __syncthreads();
    for (int i = tid; i < nedge; i += 256) col[ebase + i] = stage[i];
}

// ---- u0 = norm .* (X @ W^T) ----
__global__ __launch_bounds__(256) void k_project(const float* __restrict__ feat,
                                                 const float* __restrict__ W,
                                                 const float* __restrict__ norm,
                                                 float* __restrict__ u0) {
    __shared__ float Ws[OUTF][INF + 1];
    __shared__ float Fs[8][INF];
    int tid = threadIdx.x;
    for (int i = tid; i < OUTF * INF; i += 256) Ws[i / INF][i % INF] = W[i];
    int node0 = blockIdx.x * 8;
    for (int i = tid; i < 8 * INF; i += 256) {
        int n = node0 + i / INF;
        Fs[i / INF][i % INF] = (n < NNODES) ? feat[(size_t)n * INF + (i % INF)] : 0.0f;
    }
    __syncthreads();
    int ln = tid >> 5, of = tid & 31;
    int n = node0 + ln;
    if (n < NNODES) {
        float acc = 0.0f;
#pragma unroll
        for (int k = 0; k < INF; ++k) acc += Fs[ln][k] * Ws[of][k];
        u0[(size_t)n * OUTF + of] = acc * norm[n];
    }
}

// ---- one hop in u-space: uout[d] = w(d) * sum_e uin[col[e]]  (+bias) ----
template <bool LAST>
__global__ __launch_bounds__(256) void k_gather(const float4* __restrict__ uin,
                                                float4* __restrict__ uout,
                                                const int2* __restrict__ rowse,
                                                const int* __restrict__ col,
                                                const float* __restrict__ norm,
                                                const float4* __restrict__ bias4) {
    int t = blockIdx.x * 256 + threadIdx.x;
    int node = t >> 3;
    if (node >= NNODES) return;
    int lane = t & 7;
    int2 se = rowse[node];
    int e = se.x, re = se.y;
    float4 acc = make_float4(0.f, 0.f, 0.f, 0.f);
    for (; e + 7 < re; e += 8) {
        int s0 = col[e],     s1 = col[e + 1], s2 = col[e + 2], s3 = col[e + 3];
        int s4 = col[e + 4], s5 = col[e + 5], s6 = col[e + 6], s7 = col[e + 7];
        float4 a0 = uin[(size_t)s0 * 8 + lane];
        float4 a1 = uin[(size_t)s1 * 8 + lane];
        float4 a2 = uin[(size_t)s2 * 8 + lane];
        float4 a3 = uin[(size_t)s3 * 8 + lane];
        float4 a4 = uin[(size_t)s4 * 8 + lane];
        float4 a5 = uin[(size_t)s5 * 8 + lane];
        float4 a6 = uin[(size_t)s6 * 8 + lane];
        float4 a7 = uin[(size_t)s7 * 8 + lane];
        acc.x += ((a0.x + a1.x) + (a2.x + a3.x)) + ((a4.x + a5.x) + (a6.x + a7.x));
        acc.y += ((a0.y + a1.y) + (a2.y + a3.y)) + ((a4.y + a5.y) + (a6.y + a7.y));
        acc.z += ((a0.z + a1.z) + (a2.z + a3.z)) + ((a4.z + a5.z) + (a6.z + a7.z));
        acc.w += ((a0.w + a1.w) + (a2.w + a3.w)) + ((a4.w + a5.w) + (a6.w + a7.w));
    }
    for (; e + 3 < re; e += 4) {
        int s0 = col[e], s1 = col[e + 1], s2 = col[e + 2], s3 = col[e + 3];
        float4 a0 = uin[(size_t)s0 * 8 + lane];
        float4 a1 = uin[(size_t)s1 * 8 + lane];
        float4 a2 = uin[(size_t)s2 * 8 + lane];
        float4 a3 = uin[(size_t)s3 * 8 + lane];
        acc.x += (a0.x + a1.x) + (a2.x + a3.x);
        acc.y += (a0.y + a1.y) + (a2.y + a3.y);
        acc.z += (a0.z + a1.z) + (a2.z + a3.z);
        acc.w += (a0.w + a1.w) + (a2.w + a3.w);
    }
    for (; e < re; ++e) {
        float4 a = uin[(size_t)col[e] * 8 + lane];
        acc.x += a.x; acc.y += a.y; acc.z += a.z; acc.w += a.w;
    }
    float nn = norm[node];
    float w = LAST ? nn : nn * nn;
    acc.x *= w; acc.y *= w; acc.z *= w; acc.w *= w;
    if (LAST) {
        float4 bb = bias4[lane];
        acc.x += bb.x; acc.y += bb.y; acc.z += bb.z; acc.w += bb.w;
    }
    uout[(size_t)node * 8 + lane] = acc;
}

extern "C" void kernel_launch(void* const* d_in, const int* in_sizes, int n_in,
                              void* d_out, int out_size, void* d_ws, size_t ws_size,
                              hipStream_t stream) {
    const float* feat = (const float*)d_in[0];
    const int*   src  = (const int*)d_in[1];
    const int*   dst  = (const int*)d_in[2];
    const float* W    = (const float*)d_in[3];
    const float* b    = (const float*)d_in[4];
    float* out = (float*)d_out;

    char* ws = (char*)d_ws;
    size_t off = 0;
    auto alloc = [&](size_t bytes) {
        void* p = ws + off;
        off = (off + bytes + 255) & ~(size_t)255;
        return p;
    };
    float*    norm   = (float*)alloc((size_t)NNODES * 4);
    int2*     rowse  = (int2*)alloc((size_t)NNODES * 8);
    int*      gcur   = (int*)alloc((size_t)NBUCK * CUR_PAD * 4);
    unsigned* packed = (unsigned*)alloc((size_t)NBUCK * PLACE_CAP * 4);
    int*      col    = (int*)alloc((size_t)NBUCK * PLACE_CAP * 4);
    float*    h0     = (float*)alloc((size_t)NNODES * OUTF * 4);
    float*    h1     = (float*)alloc((size_t)NNODES * OUTF * 4);

    // ---- bucketed CSR build (no per-node histogram, no global scans) ----
    k_initcur<<<(NBUCK + 255) / 256, 256, 0, stream>>>(gcur);
    k_bin<<<(BIN_THREADS + 255) / 256, 256, 0, stream>>>(
        (const int4*)src, (const int4*)dst, gcur, packed);
    k_place<<<NBUCK, 256, 0, stream>>>(packed, gcur, col, rowse, norm);

    // ---- project 64 -> 32, pre-scaled by norm ----
    k_project<<<(NNODES + 7) / 8, 256, 0, stream>>>(feat, W, norm, h0);

    // ---- 4 hops ----
    const int ggrid = (NNODES * 8 + 255) / 256;
    k_gather<false><<<ggrid, 256, 0, stream>>>((const float4*)h0, (float4*)h1,
                                               rowse, col, norm, nullptr);
    k_gather<false><<<ggrid, 256, 0, stream>>>((const float4*)h1, (float4*)h0,
                                               rowse, col, norm, nullptr);
    k_gather<false><<<ggrid, 256, 0, stream>>>((const float4*)h0, (float4*)h1,
                                               rowse, col, norm, nullptr);
    k_gather<true><<<ggrid, 256, 0, stream>>>((const float4*)h1, (float4*)out,
                                              rowse, col, norm,
                                              (const float4*)b);
}